// Round 8
// baseline (178250.574 us; speedup 1.0000x reference)
//
#include <hip/hip_runtime.h>
#include <math.h>

#define S_LEN 131072
#define H 100
#define BLOCK 832            // 13 waves x 64; wave w owns m-tiles {2w, 2w+1}

typedef _Float16 f16;
typedef _Float16 half8 __attribute__((ext_vector_type(8)));
typedef float    f32x4 __attribute__((ext_vector_type(4)));

// Round-7 lesson: init RACE — `if(t<128) hbuf[..][t]=0` (threads 100,101) vs
// `if(t==0) hbuf[..][H]=1.0, x0` (thread 0), different waves, no barrier ->
// bias slot could end up 0 FOREVER (never rewritten) -> constant preact offset
// integrated by forget gate ~ 1e-2 output error. Fix: barrier between phases.
// Hardening: B-fragment loaded by ALL lanes (h replicated across all 16 cols)
// -> correctness independent of B's col->lane mapping; only the shared
// k-mapping (l>>4)*8+j (m90-verified GEMM pattern) + m89-verified C/D layout
// are assumed. Row-permute p=4u+g puts {i,f,g,o} of one unit in one lane's
// 4 acc regs -> in-lane c/h update, one barrier/step.
__global__ __launch_bounds__(BLOCK) void lstm_seq_kernel(
    const float* __restrict__ x,      // [S]
    const float* __restrict__ W_ih,   // [400]
    const float* __restrict__ W_hh,   // [400,100] row-major
    const float* __restrict__ b_ih,   // [400]
    const float* __restrict__ b_hh,   // [400]
    const float* __restrict__ W_out,  // [100]
    const float* __restrict__ b_out,  // [1]
    float* __restrict__ out)          // [1]
{
    // h double-buffer: k=0..99 -> h, 100 -> 1.0 (bias), 101 -> x_t, 102..127 -> 0
    __shared__ __align__(16) f16 hbuf[2][128];
    __shared__ float h32[112];        // last-step h for the final dot

    const int t    = threadIdx.x;
    const int l    = t & 63;
    const int wave = t >> 6;          // 0..12
    const int mt0  = 2 * wave;
    const int mt1  = 2 * wave + 1;    // ==25 for wave 12 -> invalid, guarded
    const int goff = (l >> 4) * 8;    // this lane-group's k-offset within a k-tile
    const bool bl  = (l & 15) == 0;   // D-col-0 lanes (verified C/D: col=lane&15)
    const int u0   = mt0 * 4 + (l >> 4);
    const int u1   = mt1 * 4 + (l >> 4);   // valid iff mt1 < 25

    // ---- A-fragments: 8 named half8 (2 m-tiles x 4 k-tiles), f16 weights ----
    auto loadA = [&](int mt, int kt) -> half8 {
        half8 r;
        int prow = mt * 16 + (l & 15);      // permuted row p = 4u + g
        int uu = prow >> 2, g = prow & 3;
        int orig = g * H + uu;              // original gate row
        const float* base = W_hh + orig * H;
        #pragma unroll
        for (int j = 0; j < 8; ++j) {
            int k = kt * 32 + goff + j;
            float v = 0.0f;
            if (mt < 25) {
                if (k < H)         v = base[k];
                else if (k == H)   v = b_ih[orig] + b_hh[orig];   // bias slot
                else if (k == H+1) v = W_ih[orig];                // x slot
            }
            r[j] = (f16)v;
        }
        return r;
    };
    half8 a00 = loadA(mt0, 0), a01 = loadA(mt0, 1),
          a02 = loadA(mt0, 2), a03 = loadA(mt0, 3);
    half8 a10 = loadA(mt1, 0), a11 = loadA(mt1, 1),
          a12 = loadA(mt1, 2), a13 = loadA(mt1, 3);
    asm volatile("" : "+v"(a00), "+v"(a01), "+v"(a02), "+v"(a03),
                      "+v"(a10), "+v"(a11), "+v"(a12), "+v"(a13));

    // ---- init h buffers: zero phase, BARRIER, then special slots ----
    if (t < 128) {
        hbuf[0][t] = (f16)0.0f;
        hbuf[1][t] = (f16)0.0f;
    }
    __syncthreads();                  // (round-7 race fix)
    if (t == 0) {
        hbuf[0][H]     = (f16)1.0f;   // bias slot, both buffers
        hbuf[1][H]     = (f16)1.0f;
        hbuf[0][H + 1] = (f16)x[0];   // x_0
    }
    float c0 = 0.0f, c1 = 0.0f;       // cell states (valid in bl lanes)
    __syncthreads();

    for (int step = 0; step < S_LEN; ++step) {
        const int p = step & 1;
        const f16* cur = hbuf[p];
        f16* nxt = hbuf[1 - p];
        int nxt_i = (step + 1 < S_LEN) ? (step + 1) : (S_LEN - 1);
        float xn = x[nxt_i];          // uniform prefetch for the x slot

        // ---- B-fragments: ALL lanes load -> h replicated across all 16 cols.
        //      Same-address within each 16-lane group: LDS broadcast, no conflict.
        half8 b0 = *(const half8*)(cur + 0  + goff);
        half8 b1 = *(const half8*)(cur + 32 + goff);
        half8 b2 = *(const half8*)(cur + 64 + goff);
        half8 b3 = *(const half8*)(cur + 96 + goff);

        // ---- gates = W_perm @ [h;1;x]  (f32 accumulate) ----
        f32x4 acc0 = {0.f, 0.f, 0.f, 0.f};
        f32x4 acc1 = {0.f, 0.f, 0.f, 0.f};
        acc0 = __builtin_amdgcn_mfma_f32_16x16x32_f16(a00, b0, acc0, 0, 0, 0);
        acc1 = __builtin_amdgcn_mfma_f32_16x16x32_f16(a10, b0, acc1, 0, 0, 0);
        acc0 = __builtin_amdgcn_mfma_f32_16x16x32_f16(a01, b1, acc0, 0, 0, 0);
        acc1 = __builtin_amdgcn_mfma_f32_16x16x32_f16(a11, b1, acc1, 0, 0, 0);
        acc0 = __builtin_amdgcn_mfma_f32_16x16x32_f16(a02, b2, acc0, 0, 0, 0);
        acc1 = __builtin_amdgcn_mfma_f32_16x16x32_f16(a12, b2, acc1, 0, 0, 0);
        acc0 = __builtin_amdgcn_mfma_f32_16x16x32_f16(a03, b3, acc0, 0, 0, 0);
        acc1 = __builtin_amdgcn_mfma_f32_16x16x32_f16(a13, b3, acc1, 0, 0, 0);

        // ---- in-lane LSTM update: D col 0, regs 0..3 = {i,f,g,o} of one unit
        if (bl) {
            {   // unit u0
                float ig = 1.0f / (1.0f + __expf(-acc0[0]));
                float fg = 1.0f / (1.0f + __expf(-acc0[1]));
                float gg = 2.0f / (1.0f + __expf(-2.0f * acc0[2])) - 1.0f;
                float og = 1.0f / (1.0f + __expf(-acc0[3]));
                c0 = __builtin_fmaf(fg, c0, ig * gg);
                float th = 2.0f / (1.0f + __expf(-2.0f * c0)) - 1.0f;
                float hv = og * th;
                nxt[u0] = (f16)hv;
                if (step == S_LEN - 1) h32[u0] = hv;
            }
            if (mt1 < 25) {  // unit u1
                float ig = 1.0f / (1.0f + __expf(-acc1[0]));
                float fg = 1.0f / (1.0f + __expf(-acc1[1]));
                float gg = 2.0f / (1.0f + __expf(-2.0f * acc1[2])) - 1.0f;
                float og = 1.0f / (1.0f + __expf(-acc1[3]));
                c1 = __builtin_fmaf(fg, c1, ig * gg);
                float th = 2.0f / (1.0f + __expf(-2.0f * c1)) - 1.0f;
                float hv = og * th;
                nxt[u1] = (f16)hv;
                if (step == S_LEN - 1) h32[u1] = hv;
            }
        }
        if (t == 0) nxt[H + 1] = (f16)xn;   // x_{t+1} into the other buffer
        __syncthreads();                     // writes(t) -> reads(t+1)
    }

    if (t == 0) {
        float s = b_out[0];
        #pragma unroll 4
        for (int j = 0; j < H; ++j) s = __builtin_fmaf(W_out[j], h32[j], s);
        out[0] = s;
    }
}

extern "C" void kernel_launch(void* const* d_in, const int* in_sizes, int n_in,
                              void* d_out, int out_size, void* d_ws, size_t ws_size,
                              hipStream_t stream) {
    const float* x     = (const float*)d_in[0];
    const float* W_ih  = (const float*)d_in[1];
    const float* W_hh  = (const float*)d_in[2];
    const float* b_ih  = (const float*)d_in[3];
    const float* b_hh  = (const float*)d_in[4];
    const float* W_out = (const float*)d_in[5];
    const float* b_out = (const float*)d_in[6];
    float* out = (float*)d_out;

    lstm_seq_kernel<<<1, BLOCK, 0, stream>>>(x, W_ih, W_hh, b_ih, b_hh,
                                             W_out, b_out, out);
}

// Round 9
// 157991.870 us; speedup vs baseline: 1.1282x; 1.1282x over previous
//
#include <hip/hip_runtime.h>
#include <math.h>

#define S_LEN 131072
#define H 100
#define BLOCK 832            // 13 waves x 64; wave w owns m-tiles {2w, 2w+1}

typedef _Float16 f16;
typedef _Float16 half8 __attribute__((ext_vector_type(8)));
typedef float    f32x4 __attribute__((ext_vector_type(4)));

// Round-8 lesson: MFMA structure + f16 numerics verified (absmax 0.0), but the
// builtin's A-operands under the 64-VGPR allocator budget got AGPR-spilled with
// per-step moves/rebuild (VGPR=36, VALUBusy 68% of CU, 2x slowdown). Fix: A
// lives in AGPRs BY DESIGN — "+a"-pinned fragments + inline-asm MFMA with "a"
// inputs (gfx950 MFMA reads A straight from AGPR). VGPR working set ~50 < 64:
// nothing to spill, nothing to remat. B replicated across all 16 cols -> all
// D cols identical -> every lane holds its unit's {i,f,g,o}: update runs
// unmasked, only ds_writes are lane-guarded. One barrier/step.
__global__ __launch_bounds__(BLOCK) void lstm_seq_kernel(
    const float* __restrict__ x,      // [S]
    const float* __restrict__ W_ih,   // [400]
    const float* __restrict__ W_hh,   // [400,100] row-major
    const float* __restrict__ b_ih,   // [400]
    const float* __restrict__ b_hh,   // [400]
    const float* __restrict__ W_out,  // [100]
    const float* __restrict__ b_out,  // [1]
    float* __restrict__ out)          // [1]
{
    // h double-buffer: k=0..99 -> h, 100 -> 1.0 (bias), 101 -> x_t, 102..127 -> 0
    __shared__ __align__(16) f16 hbuf[2][128];
    __shared__ float h32[112];        // last-step h for the final dot

    const int t    = threadIdx.x;
    const int l    = t & 63;
    const int wave = t >> 6;          // 0..12
    const int mt0  = 2 * wave;
    const int mt1  = 2 * wave + 1;    // ==25 for wave 12 -> guarded
    const int grp  = l >> 4;          // 4-lane-group id 0..3
    const int goff = grp * 8;         // k-offset of this group within a k-tile
    const bool wr_lane = (l & 15) == 0;  // one writer per group
    const int u0   = mt0 * 4 + grp;
    const int u1   = mt1 * 4 + grp;   // valid iff mt1 < 25

    // ---- A-fragments (2 m-tiles x 4 k-tiles), f16, destined for AGPRs ----
    auto loadA = [&](int mt, int kt) -> half8 {
        half8 r;
        int prow = mt * 16 + (l & 15);      // permuted row p = 4u + g
        int uu = prow >> 2, g = prow & 3;
        int orig = g * H + uu;              // original gate row
        const float* base = W_hh + orig * H;
        #pragma unroll
        for (int j = 0; j < 8; ++j) {
            int k = kt * 32 + goff + j;
            float v = 0.0f;
            if (mt < 25) {
                if (k < H)         v = base[k];
                else if (k == H)   v = b_ih[orig] + b_hh[orig];   // bias slot
                else if (k == H+1) v = W_ih[orig];                // x slot
            }
            r[j] = (f16)v;
        }
        return r;
    };
    half8 a00 = loadA(mt0, 0), a01 = loadA(mt0, 1),
          a02 = loadA(mt0, 2), a03 = loadA(mt0, 3);
    half8 a10 = loadA(mt1, 0), a11 = loadA(mt1, 1),
          a12 = loadA(mt1, 2), a13 = loadA(mt1, 3);
    // Pin into AGPRs: all later uses are "a"-constrained, so the whole live
    // range stays in the accumulator file — zero VGPR-budget pressure.
    asm volatile("" : "+a"(a00), "+a"(a01), "+a"(a02), "+a"(a03),
                      "+a"(a10), "+a"(a11), "+a"(a12), "+a"(a13));

    // ---- init h buffers: zero phase, BARRIER (round-7 race fix), specials ----
    if (t < 128) {
        hbuf[0][t] = (f16)0.0f;
        hbuf[1][t] = (f16)0.0f;
    }
    __syncthreads();
    if (t == 0) {
        hbuf[0][H]     = (f16)1.0f;   // bias slot, both buffers
        hbuf[1][H]     = (f16)1.0f;
        hbuf[0][H + 1] = (f16)x[0];   // x_0
    }
    float c0 = 0.0f, c1 = 0.0f;       // cell states (identical across a group)
    __syncthreads();

#define MFMA_A(accv, afrag, bfrag)                                        \
    asm("v_mfma_f32_16x16x32_f16 %0, %1, %2, %0"                          \
        : "+v"(accv) : "a"(afrag), "v"(bfrag))

    for (int step = 0; step < S_LEN; ++step) {
        const int p = step & 1;
        const f16* cur = hbuf[p];
        f16* nxt = hbuf[1 - p];
        int nxt_i = (step + 1 < S_LEN) ? (step + 1) : (S_LEN - 1);
        float xn = x[nxt_i];          // uniform prefetch for the x slot

        // B-fragments: all lanes load -> h replicated across all 16 B-cols
        // (uniform addr within each 16-lane group: LDS broadcast, no conflict)
        half8 b0 = *(const half8*)(cur + 0  + goff);
        half8 b1 = *(const half8*)(cur + 32 + goff);
        half8 b2 = *(const half8*)(cur + 64 + goff);
        half8 b3 = *(const half8*)(cur + 96 + goff);

        // gates = W_perm @ [h;1;x]  (f32 accumulate, A from AGPR)
        f32x4 acc0 = {0.f, 0.f, 0.f, 0.f};
        f32x4 acc1 = {0.f, 0.f, 0.f, 0.f};
        MFMA_A(acc0, a00, b0);  MFMA_A(acc1, a10, b0);
        MFMA_A(acc0, a01, b1);  MFMA_A(acc1, a11, b1);
        MFMA_A(acc0, a02, b2);  MFMA_A(acc1, a12, b2);
        MFMA_A(acc0, a03, b3);  MFMA_A(acc1, a13, b3);

        // ---- in-lane LSTM update: D cols identical, so EVERY lane holds its
        //      group's unit gates {i,f,g,o} in acc regs 0..3. Unmasked compute.
        {   // unit u0
            float ig = 1.0f / (1.0f + __expf(-acc0[0]));
            float fg = 1.0f / (1.0f + __expf(-acc0[1]));
            float gg = 2.0f / (1.0f + __expf(-2.0f * acc0[2])) - 1.0f;
            float og = 1.0f / (1.0f + __expf(-acc0[3]));
            c0 = __builtin_fmaf(fg, c0, ig * gg);
            float th = 2.0f / (1.0f + __expf(-2.0f * c0)) - 1.0f;
            float hv = og * th;
            if (wr_lane) {
                nxt[u0] = (f16)hv;
                if (step == S_LEN - 1) h32[u0] = hv;
            }
        }
        if (mt1 < 25) {  // unit u1 (uniform branch; wave 12 skips)
            float ig = 1.0f / (1.0f + __expf(-acc1[0]));
            float fg = 1.0f / (1.0f + __expf(-acc1[1]));
            float gg = 2.0f / (1.0f + __expf(-2.0f * acc1[2])) - 1.0f;
            float og = 1.0f / (1.0f + __expf(-acc1[3]));
            c1 = __builtin_fmaf(fg, c1, ig * gg);
            float th = 2.0f / (1.0f + __expf(-2.0f * c1)) - 1.0f;
            float hv = og * th;
            if (wr_lane) {
                nxt[u1] = (f16)hv;
                if (step == S_LEN - 1) h32[u1] = hv;
            }
        }
        if (t == 0) nxt[H + 1] = (f16)xn;   // x_{t+1} into the other buffer
        __syncthreads();                     // writes(t) -> reads(t+1)
    }
#undef MFMA_A

    if (t == 0) {
        float s = b_out[0];
        #pragma unroll 4
        for (int j = 0; j < H; ++j) s = __builtin_fmaf(W_out[j], h32[j], s);
        out[0] = s;
    }
}

extern "C" void kernel_launch(void* const* d_in, const int* in_sizes, int n_in,
                              void* d_out, int out_size, void* d_ws, size_t ws_size,
                              hipStream_t stream) {
    const float* x     = (const float*)d_in[0];
    const float* W_ih  = (const float*)d_in[1];
    const float* W_hh  = (const float*)d_in[2];
    const float* b_ih  = (const float*)d_in[3];
    const float* b_hh  = (const float*)d_in[4];
    const float* W_out = (const float*)d_in[5];
    const float* b_out = (const float*)d_in[6];
    float* out = (float*)d_out;

    lstm_seq_kernel<<<1, BLOCK, 0, stream>>>(x, W_ih, W_hh, b_ih, b_hh,
                                             W_out, b_out, out);
}